// Round 2
// baseline (107.285 us; speedup 1.0000x reference)
//
#include <hip/hip_runtime.h>
#include <math.h>

// feat_gan loss on MI355X.
// Shapes fixed by reference setup_inputs():
//   layer0: B=4, N0=4096, C0=64   (xyz [4,4096,3] f32, feat [4,64,4096] f32)
//   layer1: B=4, N1=1024, C1=128
// radius^2 = 1.0, nsample = 1 (first point within radius, argmax semantics).
//
// Design: one wave (64 lanes) per query point. Ballot-scan 64 src points per
// iteration; first set bit of __ballot gives the argmax-first index; early
// exit is wave-uniform. Expected chunks scanned ~1.005 (hit prob/chunk
// ~99.5% for N(0,I) data). Masked-out queries contribute exactly 0 (the
// reference zeroes both gathered groups), so they skip the gather AND the
// self ball query. Per-block partial sums go to d_ws unconditionally (no
// zero-init kernel, no atomics); a second kernel reduces 5120 partials.

#define RAD2 1.0f

constexpr int B  = 4;
constexpr int N0 = 4096, C0 = 64;
constexpr int N1 = 1024, C1 = 128;
constexpr int NB0 = (B * N0) / 4;   // 4096 blocks for layer0 (4 waves/block)
constexpr int NB1 = (B * N1) / 4;   // 1024 blocks for layer1
constexpr int NBT = NB0 + NB1;      // 5120 total

template<int C>
__device__ __forceinline__ float query_loss_wave(
    const float* __restrict__ att_xyz,   // [B,N,3] (batch-local below)
    const float* __restrict__ bat_xyz,
    const float* __restrict__ att_feat,  // [B,C,N]
    const float* __restrict__ bat_feat,
    int N, int b, int n, int lane)
{
    const float* aq = att_xyz + (size_t)b * N * 3;
    const float* bq = bat_xyz + (size_t)b * N * 3;

    // query point (wave-uniform scalar loads)
    const float qx = bq[n * 3 + 0];
    const float qy = bq[n * 3 + 1];
    const float qz = bq[n * 3 + 2];

    // --- ball query over att: first m with d2 < 1 (argmax-first semantics) ---
    int att_idx = -1;
    for (int c0 = 0; c0 < N; c0 += 64) {
        const int m = c0 + lane;                    // N % 64 == 0, always valid
        const float dx = qx - aq[m * 3 + 0];
        const float dy = qy - aq[m * 3 + 1];
        const float dz = qz - aq[m * 3 + 2];
        const unsigned long long bal =
            __ballot(dx * dx + dy * dy + dz * dz < RAD2);
        if (bal) { att_idx = c0 + (int)__builtin_ctzll(bal); break; }
    }
    if (att_idx < 0) return 0.0f;                   // mask=false -> zero contribution

    // --- self ball query over bat: guaranteed hit at m == n ---
    int bat_idx = n;
    for (int c0 = 0; c0 < N; c0 += 64) {
        const int m = c0 + lane;
        const float dx = qx - bq[m * 3 + 0];
        const float dy = qy - bq[m * 3 + 1];
        const float dz = qz - bq[m * 3 + 2];
        const unsigned long long bal =
            __ballot(dx * dx + dy * dy + dz * dz < RAD2);
        if (bal) { bat_idx = c0 + (int)__builtin_ctzll(bal); break; }
    }

    // --- gather + squared diff: lanes 0-2 xyz, lane c feature channel c ---
    float part = 0.0f;
    if (lane < 3) {
        const float d = aq[att_idx * 3 + lane] - bq[bat_idx * 3 + lane];
        part += d * d;
    }
    const float* af = att_feat + (size_t)b * C * N;
    const float* bf = bat_feat + (size_t)b * C * N;
    #pragma unroll
    for (int c = lane; c < C; c += 64) {
        const float d = af[(size_t)c * N + att_idx] - bf[(size_t)c * N + bat_idx];
        part += d * d;
    }
    return part;
}

__global__ __launch_bounds__(256) void fg_fused_kernel(
    const float* __restrict__ att_xyz0, const float* __restrict__ bat_xyz0,
    const float* __restrict__ att_feat0, const float* __restrict__ bat_feat0,
    const float* __restrict__ att_xyz1, const float* __restrict__ bat_xyz1,
    const float* __restrict__ att_feat1, const float* __restrict__ bat_feat1,
    double* __restrict__ partials)       // [NBT], written unconditionally
{
    const int lane = threadIdx.x & 63;
    const int wid  = threadIdx.x >> 6;
    const int blk  = blockIdx.x;

    float part;
    if (blk < NB0) {
        const int gw = blk * 4 + wid;
        const int b = gw >> 12;                     // / N0
        const int n = gw & (N0 - 1);
        part = query_loss_wave<C0>(att_xyz0, bat_xyz0, att_feat0, bat_feat0,
                                   N0, b, n, lane);
    } else {
        const int gw = (blk - NB0) * 4 + wid;
        const int b = gw >> 10;                     // / N1
        const int n = gw & (N1 - 1);
        part = query_loss_wave<C1>(att_xyz1, bat_xyz1, att_feat1, bat_feat1,
                                   N1, b, n, lane);
    }

    // wave reduce (64 lanes)
    #pragma unroll
    for (int off = 32; off > 0; off >>= 1)
        part += __shfl_down(part, off);

    __shared__ float wpart[4];
    if (lane == 0) wpart[wid] = part;
    __syncthreads();                                // every thread reaches this
    if (threadIdx.x == 0)
        partials[blk] = (double)(wpart[0] + wpart[1] + wpart[2] + wpart[3]);
}

__global__ __launch_bounds__(512) void fg_finalize_kernel(
    const double* __restrict__ partials,
    float* __restrict__ out)
{
    const int t = threadIdx.x;
    double s0 = 0.0, s1 = 0.0;
    for (int i = t; i < NB0; i += 512) s0 += partials[i];
    for (int i = NB0 + t; i < NBT; i += 512) s1 += partials[i];

    __shared__ double sh0[8], sh1[8];
    #pragma unroll
    for (int off = 32; off > 0; off >>= 1) {
        s0 += __shfl_down(s0, off);
        s1 += __shfl_down(s1, off);
    }
    const int lane = t & 63, wid = t >> 6;
    if (lane == 0) { sh0[wid] = s0; sh1[wid] = s1; }
    __syncthreads();
    if (t == 0) {
        double a0 = 0.0, a1 = 0.0;
        #pragma unroll
        for (int w = 0; w < 8; ++w) { a0 += sh0[w]; a1 += sh1[w]; }
        const double l0 = a0 * (1.0 / ((double)B * N0 * (3 + C0)));
        const double l1 = a1 * (1.0 / ((double)B * N1 * (3 + C1)));
        double loss = 0.5 * (l0 + l1);
        if (isnan(loss)) loss = l1;     // reference: where(isnan, losses[-1], loss)
        out[0] = (float)loss;
    }
}

extern "C" void kernel_launch(void* const* d_in, const int* in_sizes, int n_in,
                              void* d_out, int out_size, void* d_ws, size_t ws_size,
                              hipStream_t stream) {
    // setup_inputs order:
    // 0 att_xyz0  1 att_xyz1  2 bat_xyz0  3 bat_xyz1
    // 4 att_feat0 5 att_feat1 6 bat_feat0 7 bat_feat1
    const float* att_xyz0  = (const float*)d_in[0];
    const float* att_xyz1  = (const float*)d_in[1];
    const float* bat_xyz0  = (const float*)d_in[2];
    const float* bat_xyz1  = (const float*)d_in[3];
    const float* att_feat0 = (const float*)d_in[4];
    const float* att_feat1 = (const float*)d_in[5];
    const float* bat_feat0 = (const float*)d_in[6];
    const float* bat_feat1 = (const float*)d_in[7];
    float* out = (float*)d_out;

    double* partials = (double*)d_ws;   // NBT doubles = 40 KiB of scratch

    fg_fused_kernel<<<NBT, 256, 0, stream>>>(
        att_xyz0, bat_xyz0, att_feat0, bat_feat0,
        att_xyz1, bat_xyz1, att_feat1, bat_feat1, partials);

    fg_finalize_kernel<<<1, 512, 0, stream>>>(partials, out);
}